// Round 1
// baseline (378.338 us; speedup 1.0000x reference)
//
#include <hip/hip_runtime.h>

#define NFFT 16000   // 128 * 125
#define BATCH 128
#define DIM 2048

__device__ __forceinline__ float2 cmul(float2 a, float2 b) {
    return make_float2(a.x * b.x - a.y * b.y, a.x * b.y + a.y * b.x);
}

// 3-digit base-5 reversal (involution), n in [0,125)
__device__ __forceinline__ int rev5_3(int n) {
    int d0 = n % 5, r = n / 5;
    int d1 = r % 5, d2 = r / 5;
    return d0 * 25 + d1 * 5 + d2;
}

// ---- K3: twiddle table W[j] = exp(-2*pi*i*j/16000), f64-generated ----
__global__ void gen_twiddles(float2* W) {
    int j = blockIdx.x * blockDim.x + threadIdx.x;
    if (j < NFFT) {
        double a = -2.0 * 3.141592653589793238462643383279502884 * (double)j / (double)NFFT;
        W[j] = make_float2((float)cos(a), (float)sin(a));
    }
}

// ---- K1: find the single nonzero (idx, sign) in each row of C1/C2 ----
// one wave per row, float4 scan with wave-uniform early exit
__global__ void extract_sketch(const float* __restrict__ C1, const float* __restrict__ C2,
                               int* __restrict__ idx1, float* __restrict__ sgn1,
                               int* __restrict__ idx2, float* __restrict__ sgn2) {
    int gwave = (blockIdx.x * blockDim.x + threadIdx.x) >> 6;
    int lane = threadIdx.x & 63;
    if (gwave >= 2 * DIM) return;
    const float* row;
    int* idxp; float* sgnp; int d;
    if (gwave < DIM) { d = gwave;       row = C1 + (size_t)d * NFFT; idxp = idx1; sgnp = sgn1; }
    else             { d = gwave - DIM; row = C2 + (size_t)d * NFFT; idxp = idx2; sgnp = sgn2; }
    for (int it = 0; it < 63; ++it) {               // 63*256 = 16128 >= 16000
        int off = it * 256 + lane * 4;
        float4 v = make_float4(0.f, 0.f, 0.f, 0.f);
        if (off < NFFT) v = *reinterpret_cast<const float4*>(row + off);
        bool found = (v.x != 0.f) || (v.y != 0.f) || (v.z != 0.f) || (v.w != 0.f);
        if (found) {
            int j; float s;
            if (v.x != 0.f)      { j = 0; s = v.x; }
            else if (v.y != 0.f) { j = 1; s = v.y; }
            else if (v.z != 0.f) { j = 2; s = v.z; }
            else                 { j = 3; s = v.w; }
            idxp[d] = off + j;
            sgnp[d] = s;
        }
        if (__any(found)) break;                    // wave-uniform
    }
}

// ---- K2: zero the packed-signal buffer ----
__global__ void zero4(float4* p, int n4) {
    int t = blockIdx.x * blockDim.x + threadIdx.x;
    if (t < n4) p[t] = make_float4(0.f, 0.f, 0.f, 0.f);
}

// ---- K4: scatter-build z[b][p] = y1[b][p] + i*y2[b][p] ----
__global__ void sketch_scatter(const float* __restrict__ x1, const float* __restrict__ x2,
                               const int* __restrict__ idx1, const float* __restrict__ sgn1,
                               const int* __restrict__ idx2, const float* __restrict__ sgn2,
                               float* __restrict__ zf) {
    int t = blockIdx.x * blockDim.x + threadIdx.x;
    if (t >= BATCH * DIM) return;
    int b = t >> 11;            // t = b*2048 + d
    int d = t & (DIM - 1);
    float v1 = sgn1[d] * x1[t];
    float v2 = sgn2[d] * x2[t];
    atomicAdd(zf + ((size_t)b * NFFT + idx1[d]) * 2,     v1);
    atomicAdd(zf + ((size_t)b * NFFT + idx2[d]) * 2 + 1, v2);
}

// ---- shared FFT-16000 core: data in LDS, layout T[n1][n2'] = ld[n1*125 + n2'] ----
// Expects input loaded as ld[n1*125 + rev5_3(n2)] = x[n1 + 128*n2].
// Produces X[k] at ld[k] (natural order) since k2 + 125*k1 == LDS index k1*125 + k2.
__device__ void fft16000(float2* ld, const float2* __restrict__ W) {
    const int tid = threadIdx.x;
    const int nt = blockDim.x;
    const float C1_5 = 0.30901699437494742f, S1_5 = 0.95105651629515357f;
    const float C2_5 = -0.80901699437494745f, S2_5 = 0.58778525229247312f;
    const float2 w5tab[5] = { make_float2(1.f, 0.f),
                              make_float2(C1_5, -S1_5), make_float2(C2_5, -S2_5),
                              make_float2(C2_5,  S2_5), make_float2(C1_5,  S1_5) };

    // Stage I: 128 independent 125-point FFTs (radix-5 DIT, 3 stages)
    #pragma unroll
    for (int s = 0; s < 3; ++s) {
        const int m = (s == 0) ? 1 : (s == 1) ? 5 : 25;
        const int twmul = NFFT / (5 * m);           // W_{5m}^t = W_N^{twmul*t}
        for (int task = tid; task < 128 * 25; task += nt) {
            int n1 = task / 25;
            int bf = task % 25;
            int t = bf % m, blk = bf / m;
            int base = n1 * 125 + blk * (5 * m) + t;
            float2 xv[5];
            #pragma unroll
            for (int r = 0; r < 5; ++r) xv[r] = ld[base + r * m];
            if (m > 1) {
                int step = twmul * t;               // < 16000 for all stages
                #pragma unroll
                for (int r = 1; r < 5; ++r) xv[r] = cmul(xv[r], W[step * r]);
            }
            float2 y[5];
            #pragma unroll
            for (int q = 0; q < 5; ++q) {
                float2 acc = xv[0];
                #pragma unroll
                for (int r = 1; r < 5; ++r) {
                    float2 t2 = cmul(xv[r], w5tab[(q * r) % 5]);
                    acc.x += t2.x; acc.y += t2.y;
                }
                y[q] = acc;
            }
            #pragma unroll
            for (int q = 0; q < 5; ++q) ld[base + q * m] = y[q];
        }
        __syncthreads();
    }

    // Stage II: twiddle by W_N^{n1*k2} (source position), then bit-reverse swap over n1
    for (int idx = tid; idx < NFFT; idx += nt) {
        int n1 = idx / 125;
        int k2 = idx - n1 * 125;
        int rn1 = (int)(__brev((unsigned)n1) >> 25);   // 7-bit reversal
        if (n1 > rn1) continue;                        // each pair handled once
        int pb = rn1 * 125 + k2;
        float2 va = ld[idx], vb = ld[pb];
        va = cmul(va, W[n1 * k2]);                     // n1*k2 <= 127*124 < 16000
        vb = cmul(vb, W[rn1 * k2]);
        ld[idx] = vb;
        ld[pb] = va;
    }
    __syncthreads();

    // Stage III: 125 independent 128-point FFTs over n1 (radix-2 DIT, 7 stages)
    #pragma unroll
    for (int s = 0; s < 7; ++s) {
        const int m = 1 << s;
        const int twmul = NFFT >> (s + 1);          // W_{2m}^t = W_N^{twmul*t}
        for (int task = tid; task < 125 * 64; task += nt) {
            int bf = task / 125;                    // butterfly 0..63
            int k2 = task - bf * 125;
            int t = bf & (m - 1);
            int blk = bf >> s;
            int pa = (blk * 2 * m + t) * 125 + k2;
            int pb = pa + m * 125;
            float2 a = ld[pa], b = ld[pb];
            float2 wb = cmul(W[twmul * t], b);
            ld[pa] = make_float2(a.x + wb.x, a.y + wb.y);
            ld[pb] = make_float2(a.x - wb.x, a.y - wb.y);
        }
        __syncthreads();
    }
}

// ---- K5: forward FFT of packed z (in-place in ws: z -> Z) ----
__global__ void fft_fwd_kernel(float2* z, const float2* __restrict__ W) {
    extern __shared__ float2 ld[];
    const int b = blockIdx.x;
    const int tid = threadIdx.x, nt = blockDim.x;
    float2* zb = z + (size_t)b * NFFT;
    for (int n = tid; n < NFFT; n += nt) {
        float2 v = zb[n];
        int n1 = n & 127, n2 = n >> 7;
        ld[n1 * 125 + rev5_3(n2)] = v;
    }
    __syncthreads();
    fft16000(ld, W);
    for (int k = tid; k < NFFT; k += nt) zb[k] = ld[k];
}

// ---- K6: G = F1*F2 from packed spectrum, then IFFT via conj-FFT-conj, real part ----
// F1*F2 = (Z[k]^2 - conj(Z[N-k])^2) / (4i);  IFFT(G) = conj(FFT(conj(G)))/N
__global__ void fft_inv_kernel(const float2* __restrict__ Z, float* __restrict__ out,
                               const float2* __restrict__ W) {
    extern __shared__ float2 ld[];
    const int b = blockIdx.x;
    const int tid = threadIdx.x, nt = blockDim.x;
    const float2* Zb = Z + (size_t)b * NFFT;
    for (int k = tid; k < NFFT; k += nt) {
        float2 Zk = Zb[k];
        int km = (k == 0) ? 0 : (NFFT - k);
        float2 Zm = Zb[km];
        // x = Zk^2 - conj(Zm)^2 = (u, v)
        float u = (Zk.x * Zk.x - Zk.y * Zk.y) - (Zm.x * Zm.x - Zm.y * Zm.y);
        float v = 2.f * (Zk.x * Zk.y + Zm.x * Zm.y);
        // conj(G) = conj(x/(4i)) = (v/4, u/4)
        float2 val = make_float2(0.25f * v, 0.25f * u);
        int n1 = k & 127, n2 = k >> 7;
        ld[n1 * 125 + rev5_3(n2)] = val;
    }
    __syncthreads();
    fft16000(ld, W);
    const float invN = 1.0f / (float)NFFT;
    for (int k = tid; k < NFFT; k += nt)
        out[(size_t)b * NFFT + k] = ld[k].x * invN;   // Re(conj(.)) = Re(.)
}

extern "C" void kernel_launch(void* const* d_in, const int* in_sizes, int n_in,
                              void* d_out, int out_size, void* d_ws, size_t ws_size,
                              hipStream_t stream) {
    (void)in_sizes; (void)n_in; (void)out_size; (void)ws_size;
    const float* x1 = (const float*)d_in[0];
    const float* x2 = (const float*)d_in[1];
    const float* C1 = (const float*)d_in[2];
    const float* C2 = (const float*)d_in[3];
    float* out = (float*)d_out;

    // workspace layout (16B-aligned offsets), total ~16.6 MB
    char* w = (char*)d_ws;
    float*  zf   = (float*)(w);                 // 128*16000 float2 = 16,384,000 B (z, then Z in-place)
    int*    idx1 = (int*)  (w + 16384000);      // 8 KB
    float*  sgn1 = (float*)(w + 16392192);      // 8 KB
    int*    idx2 = (int*)  (w + 16400384);      // 8 KB
    float*  sgn2 = (float*)(w + 16408576);      // 8 KB
    float2* W    = (float2*)(w + 16416768);     // 16000 float2 = 128 KB

    // allow 128 KB dynamic LDS (CDNA4: 160 KiB/CU)
    (void)hipFuncSetAttribute((const void*)fft_fwd_kernel,
                              hipFuncAttributeMaxDynamicSharedMemorySize, NFFT * 8);
    (void)hipFuncSetAttribute((const void*)fft_inv_kernel,
                              hipFuncAttributeMaxDynamicSharedMemorySize, NFFT * 8);

    gen_twiddles  <<<63, 256, 0, stream>>>(W);
    extract_sketch<<<(2 * DIM) / 4, 256, 0, stream>>>(C1, C2, idx1, sgn1, idx2, sgn2);
    zero4         <<<4000, 256, 0, stream>>>((float4*)zf, BATCH * NFFT * 2 / 4);
    sketch_scatter<<<(BATCH * DIM) / 256, 256, 0, stream>>>(x1, x2, idx1, sgn1, idx2, sgn2, zf);
    fft_fwd_kernel<<<BATCH, 1024, NFFT * 8, stream>>>((float2*)zf, W);
    fft_inv_kernel<<<BATCH, 1024, NFFT * 8, stream>>>((const float2*)zf, out, W);
}

// Round 2
// 356.276 us; speedup vs baseline: 1.0619x; 1.0619x over previous
//
#include <hip/hip_runtime.h>

#define NFFT 16000   // 128 * 125
#define BATCH 128
#define DIM 2048

__device__ __forceinline__ float2 cmul(float2 a, float2 b) {
    return make_float2(a.x * b.x - a.y * b.y, a.x * b.y + a.y * b.x);
}

// 3-digit base-5 reversal (involution), n in [0,125)
__device__ __forceinline__ int rev5_3(int n) {
    int d0 = n % 5, r = n / 5;
    int d1 = r % 5, d2 = r / 5;
    return d0 * 25 + d1 * 5 + d2;
}

// permuted LDS slot for signal position p: ld[(p&127)*125 + rev5_3(p>>7)]
__device__ __forceinline__ int perm_slot(int p) {
    return (p & 127) * 125 + rev5_3(p >> 7);
}

// ---- twiddle table W[j] = exp(-2*pi*i*j/16000), f64-generated ----
__global__ void gen_twiddles(float2* W) {
    int j = blockIdx.x * blockDim.x + threadIdx.x;
    if (j < NFFT) {
        double a = -2.0 * 3.141592653589793238462643383279502884 * (double)j / (double)NFFT;
        W[j] = make_float2((float)cos(a), (float)sin(a));
    }
}

// ---- find the single nonzero (idx, sign) in each row of C1/C2 ----
// one wave per row, float4 scan with wave-uniform early exit (HBM-bound, ~131 MB expected)
__global__ void extract_sketch(const float* __restrict__ C1, const float* __restrict__ C2,
                               int* __restrict__ idx1, float* __restrict__ sgn1,
                               int* __restrict__ idx2, float* __restrict__ sgn2) {
    int gwave = (blockIdx.x * blockDim.x + threadIdx.x) >> 6;
    int lane = threadIdx.x & 63;
    if (gwave >= 2 * DIM) return;
    const float* row;
    int* idxp; float* sgnp; int d;
    if (gwave < DIM) { d = gwave;       row = C1 + (size_t)d * NFFT; idxp = idx1; sgnp = sgn1; }
    else             { d = gwave - DIM; row = C2 + (size_t)d * NFFT; idxp = idx2; sgnp = sgn2; }
    for (int it = 0; it < 63; ++it) {               // 63*256 = 16128 >= 16000
        int off = it * 256 + lane * 4;
        float4 v = make_float4(0.f, 0.f, 0.f, 0.f);
        if (off < NFFT) v = *reinterpret_cast<const float4*>(row + off);
        bool found = (v.x != 0.f) || (v.y != 0.f) || (v.z != 0.f) || (v.w != 0.f);
        if (found) {
            int j; float s;
            if (v.x != 0.f)      { j = 0; s = v.x; }
            else if (v.y != 0.f) { j = 1; s = v.y; }
            else if (v.z != 0.f) { j = 2; s = v.z; }
            else                 { j = 3; s = v.w; }
            idxp[d] = off + j;
            sgnp[d] = s;
        }
        if (__any(found)) break;                    // wave-uniform
    }
}

// ---- shared FFT-16000 core: data in LDS, layout T[n1][n2'] = ld[n1*125 + n2'] ----
// Expects input loaded as ld[n1*125 + rev5_3(n2)] = x[n1 + 128*n2]  (= perm_slot).
// Produces X[k] at ld[k] (natural order).
__device__ void fft16000(float2* ld, const float2* __restrict__ W) {
    const int tid = threadIdx.x;
    const int nt = blockDim.x;
    const float C1_5 = 0.30901699437494742f, S1_5 = 0.95105651629515357f;
    const float C2_5 = -0.80901699437494745f, S2_5 = 0.58778525229247312f;
    const float2 w5tab[5] = { make_float2(1.f, 0.f),
                              make_float2(C1_5, -S1_5), make_float2(C2_5, -S2_5),
                              make_float2(C2_5,  S2_5), make_float2(C1_5,  S1_5) };

    // Stage I: 128 independent 125-point FFTs (radix-5 DIT, 3 stages)
    #pragma unroll
    for (int s = 0; s < 3; ++s) {
        const int m = (s == 0) ? 1 : (s == 1) ? 5 : 25;
        const int twmul = NFFT / (5 * m);           // W_{5m}^t = W_N^{twmul*t}
        for (int task = tid; task < 128 * 25; task += nt) {
            int n1 = task / 25;
            int bf = task % 25;
            int t = bf % m, blk = bf / m;
            int base = n1 * 125 + blk * (5 * m) + t;
            float2 xv[5];
            #pragma unroll
            for (int r = 0; r < 5; ++r) xv[r] = ld[base + r * m];
            if (m > 1) {
                int step = twmul * t;
                #pragma unroll
                for (int r = 1; r < 5; ++r) xv[r] = cmul(xv[r], W[step * r]);
            }
            float2 y[5];
            #pragma unroll
            for (int q = 0; q < 5; ++q) {
                float2 acc = xv[0];
                #pragma unroll
                for (int r = 1; r < 5; ++r) {
                    float2 t2 = cmul(xv[r], w5tab[(q * r) % 5]);
                    acc.x += t2.x; acc.y += t2.y;
                }
                y[q] = acc;
            }
            #pragma unroll
            for (int q = 0; q < 5; ++q) ld[base + q * m] = y[q];
        }
        __syncthreads();
    }

    // Stage II: twiddle by W_N^{n1*k2} (source position), then bit-reverse swap over n1
    for (int idx = tid; idx < NFFT; idx += nt) {
        int n1 = idx / 125;
        int k2 = idx - n1 * 125;
        int rn1 = (int)(__brev((unsigned)n1) >> 25);   // 7-bit reversal
        if (n1 > rn1) continue;
        int pb = rn1 * 125 + k2;
        float2 va = ld[idx], vb = ld[pb];
        va = cmul(va, W[n1 * k2]);
        vb = cmul(vb, W[rn1 * k2]);
        ld[idx] = vb;
        ld[pb] = va;
    }
    __syncthreads();

    // Stage III: 125 independent 128-point FFTs over n1 (radix-2 DIT, 7 stages)
    #pragma unroll
    for (int s = 0; s < 7; ++s) {
        const int m = 1 << s;
        const int twmul = NFFT >> (s + 1);
        for (int task = tid; task < 125 * 64; task += nt) {
            int bf = task / 125;
            int k2 = task - bf * 125;
            int t = bf & (m - 1);
            int blk = bf >> s;
            int pa = (blk * 2 * m + t) * 125 + k2;
            int pb = pa + m * 125;
            float2 a = ld[pa], b = ld[pb];
            float2 wb = cmul(W[twmul * t], b);
            ld[pa] = make_float2(a.x + wb.x, a.y + wb.y);
            ld[pb] = make_float2(a.x - wb.x, a.y - wb.y);
        }
        __syncthreads();
    }
}

// ---- fused: scatter -> FFT -> pointwise (packed-spectrum unpack) -> IFFT -> real ----
// z[b][p] = y1[b][p] + i*y2[b][p]  (one forward FFT per batch instead of two)
// F1*F2 = (Z[k]^2 - conj(Z[N-k])^2) / (4i);  IFFT(G) = conj(FFT(conj(G)))/N
// G is conj-symmetric so val(N-k) = conj(val(k)): one pair-task produces both.
__global__ void fused_fft(const float* __restrict__ x1, const float* __restrict__ x2,
                          const int* __restrict__ idx1, const float* __restrict__ sgn1,
                          const int* __restrict__ idx2, const float* __restrict__ sgn2,
                          float* __restrict__ out, const float2* __restrict__ W) {
    extern __shared__ float2 ld[];
    const int b = blockIdx.x;
    const int tid = threadIdx.x, nt = blockDim.x;

    // zero LDS
    for (int i = tid; i < NFFT; i += nt) ld[i] = make_float2(0.f, 0.f);
    __syncthreads();

    // scatter x1/x2 directly into permuted LDS layout via LDS float atomics
    const float* x1b = x1 + (size_t)b * DIM;
    const float* x2b = x2 + (size_t)b * DIM;
    for (int d = tid; d < DIM; d += nt) {
        float v1 = sgn1[d] * x1b[d];
        atomicAdd(&ld[perm_slot(idx1[d])].x, v1);
        float v2 = sgn2[d] * x2b[d];
        atomicAdd(&ld[perm_slot(idx2[d])].y, v2);
    }
    __syncthreads();

    fft16000(ld, W);   // Z now at natural positions

    // pointwise pairs (k, N-k), k in [0, 8000]; values staged in registers so the
    // write doubles as the input permutation of the second FFT (no LDS ping-pong)
    float2 vals[8][2];
    int nk = 0;
    for (int k = tid; k <= NFFT / 2; k += nt) {
        int m = (k == 0) ? 0 : NFFT - k;
        float2 Zk = ld[k], Zm = ld[m];
        float u = (Zk.x * Zk.x - Zk.y * Zk.y) - (Zm.x * Zm.x - Zm.y * Zm.y);
        float v = 2.f * (Zk.x * Zk.y + Zm.x * Zm.y);
        vals[nk][0] = make_float2(0.25f * v,  0.25f * u);   // conj(G)[k]
        vals[nk][1] = make_float2(0.25f * v, -0.25f * u);   // conj(G)[N-k] = conj(conj(G)[k])
        ++nk;
    }
    __syncthreads();   // all reads of Z done
    nk = 0;
    for (int k = tid; k <= NFFT / 2; k += nt) {
        ld[perm_slot(k)] = vals[nk][0];
        if (k != 0 && k != NFFT / 2)
            ld[perm_slot(NFFT - k)] = vals[nk][1];
        ++nk;
    }
    __syncthreads();

    fft16000(ld, W);   // FFT(conj(G)); Re(conj(.)) = Re(.)

    const float invN = 1.0f / (float)NFFT;
    float* outb = out + (size_t)b * NFFT;
    for (int k = tid; k < NFFT; k += nt) outb[k] = ld[k].x * invN;
}

extern "C" void kernel_launch(void* const* d_in, const int* in_sizes, int n_in,
                              void* d_out, int out_size, void* d_ws, size_t ws_size,
                              hipStream_t stream) {
    (void)in_sizes; (void)n_in; (void)out_size; (void)ws_size;
    const float* x1 = (const float*)d_in[0];
    const float* x2 = (const float*)d_in[1];
    const float* C1 = (const float*)d_in[2];
    const float* C2 = (const float*)d_in[3];
    float* out = (float*)d_out;

    // workspace layout: idx/sgn tables + twiddle table (z buffer eliminated)
    char* w = (char*)d_ws;
    int*    idx1 = (int*)  (w);             // 8 KB
    float*  sgn1 = (float*)(w + 8192);      // 8 KB
    int*    idx2 = (int*)  (w + 16384);     // 8 KB
    float*  sgn2 = (float*)(w + 24576);     // 8 KB
    float2* W    = (float2*)(w + 32768);    // 16000 float2 = 128 KB

    // allow 128 KB dynamic LDS (CDNA4: 160 KiB/CU)
    (void)hipFuncSetAttribute((const void*)fused_fft,
                              hipFuncAttributeMaxDynamicSharedMemorySize, NFFT * 8);

    gen_twiddles  <<<63, 256, 0, stream>>>(W);
    extract_sketch<<<(2 * DIM) / 4, 256, 0, stream>>>(C1, C2, idx1, sgn1, idx2, sgn2);
    fused_fft     <<<BATCH, 1024, NFFT * 8, stream>>>(x1, x2, idx1, sgn1, idx2, sgn2, out, W);
}

// Round 3
// 319.988 us; speedup vs baseline: 1.1823x; 1.1134x over previous
//
#include <hip/hip_runtime.h>

#define NFFT 16000   // 128 * 125
#define BATCH 128
#define DIM 2048

__device__ __forceinline__ float2 cmul(float2 a, float2 b) {
    return make_float2(a.x * b.x - a.y * b.y, a.x * b.y + a.y * b.x);
}
__device__ __forceinline__ float2 cadd(float2 a, float2 b) { return make_float2(a.x + b.x, a.y + b.y); }
__device__ __forceinline__ float2 csub(float2 a, float2 b) { return make_float2(a.x - b.x, a.y - b.y); }
// exp(i*ang) via native v_sin/v_cos (pass negative ang for W^+j)
__device__ __forceinline__ float2 cis(float ang) { return make_float2(__cosf(ang), __sinf(ang)); }

// 3-digit base-5 reversal (involution), n in [0,125)
__device__ __forceinline__ int rev5_3(int n) {
    int d0 = n % 5, r = n / 5;
    int d1 = r % 5, d2 = r / 5;
    return d0 * 25 + d1 * 5 + d2;
}

// LDS slot for signal position p (input layout of fft16000): ld[(p&127)*125 + rev5_3(p>>7)]
__device__ __forceinline__ int perm_slot(int p) {
    return (p & 127) * 125 + rev5_3(p >> 7);
}

// output row permutation of the DIF n1-transform, stage radices [4,4,4,2]:
// spectrum Z[k2 + 125*k1] lands at ld[posn1(k1)*125 + k2]
__device__ __forceinline__ int posn1(int k) {
    return ((k & 3) << 5) | (((k >> 2) & 3) << 3) | (((k >> 4) & 3) << 1) | (k >> 6);
}

// ---- find the single nonzero (idx, sign) in each row of C1/C2 ----
// one wave per row; 4 independent float4 loads in flight per exit-check step
__global__ void extract_sketch(const float* __restrict__ C1, const float* __restrict__ C2,
                               int* __restrict__ idx1, float* __restrict__ sgn1,
                               int* __restrict__ idx2, float* __restrict__ sgn2) {
    int gwave = (blockIdx.x * blockDim.x + threadIdx.x) >> 6;
    int lane = threadIdx.x & 63;
    if (gwave >= 2 * DIM) return;
    const float* row;
    int* idxp; float* sgnp; int d;
    if (gwave < DIM) { d = gwave;       row = C1 + (size_t)d * NFFT; idxp = idx1; sgnp = sgn1; }
    else             { d = gwave - DIM; row = C2 + (size_t)d * NFFT; idxp = idx2; sgnp = sgn2; }
    for (int step = 0; step < 16; ++step) {         // 16 * 4KB = 64KB >= 16000 floats
        int off0 = step * 1024 + lane * 4;
        float4 v[4];
        #pragma unroll
        for (int c = 0; c < 4; ++c) {
            int off = off0 + c * 256;
            v[c] = (off < NFFT) ? *reinterpret_cast<const float4*>(row + off)
                                : make_float4(0.f, 0.f, 0.f, 0.f);
        }
        bool found = false;
        #pragma unroll
        for (int c = 0; c < 4; ++c) {
            float4 w = v[c];
            if (w.x != 0.f || w.y != 0.f || w.z != 0.f || w.w != 0.f) {
                int off = off0 + c * 256;
                int j; float s;
                if (w.x != 0.f)      { j = 0; s = w.x; }
                else if (w.y != 0.f) { j = 1; s = w.y; }
                else if (w.z != 0.f) { j = 2; s = w.z; }
                else                 { j = 3; s = w.w; }
                idxp[d] = off + j;
                sgnp[d] = s;
                found = true;
            }
        }
        if (__any(found)) return;                   // wave-uniform exit
    }
}

// ---- FFT-16000 core, all twiddles inline (no table) ----
// Input: signal x[n] at ld[perm_slot(n)], n = n1 + 128*n2.
// Output: Z[k2 + 125*k1] at ld[posn1(k1)*125 + k2].
// Structure: 3x radix-5 DIT over n2, then radix-4 DIF over n1 with the
// inter-dimension twiddle W_N^{n1*k2} fused into the first DIF stage.
__device__ void fft16000(float2* ld) {
    const int tid = threadIdx.x, nt = blockDim.x;
    const float C1_5 = 0.30901699437494742f, S1_5 = 0.95105651629515357f;
    const float C2_5 = -0.80901699437494745f, S2_5 = 0.58778525229247312f;
    const float2 w5tab[5] = { make_float2(1.f, 0.f),
                              make_float2(C1_5, -S1_5), make_float2(C2_5, -S2_5),
                              make_float2(C2_5,  S2_5), make_float2(C1_5,  S1_5) };

    // Stage I: 128 independent 125-point FFTs (radix-5 DIT, 3 stages)
    #pragma unroll
    for (int s = 0; s < 3; ++s) {
        const int m = (s == 0) ? 1 : (s == 1) ? 5 : 25;
        const float angstep = -6.28318530717958647692f / (float)(5 * m);
        for (int task = tid; task < 128 * 25; task += nt) {
            int n1 = task / 25;
            int bf = task - n1 * 25;
            int t = bf % m, blk = bf / m;
            int base = n1 * 125 + blk * (5 * m) + t;
            float2 xv[5];
            #pragma unroll
            for (int r = 0; r < 5; ++r) xv[r] = ld[base + r * m];
            if (m > 1) {
                float2 w1 = cis(angstep * (float)t);
                float2 w2 = cmul(w1, w1);
                float2 w3 = cmul(w2, w1);
                float2 w4 = cmul(w2, w2);
                xv[1] = cmul(xv[1], w1); xv[2] = cmul(xv[2], w2);
                xv[3] = cmul(xv[3], w3); xv[4] = cmul(xv[4], w4);
            }
            float2 y[5];
            #pragma unroll
            for (int q = 0; q < 5; ++q) {
                float2 acc = xv[0];
                #pragma unroll
                for (int r = 1; r < 5; ++r) {
                    float2 t2 = cmul(xv[r], w5tab[(q * r) % 5]);
                    acc.x += t2.x; acc.y += t2.y;
                }
                y[q] = acc;
            }
            #pragma unroll
            for (int q = 0; q < 5; ++q) ld[base + q * m] = y[q];
        }
        __syncthreads();
    }

    // Stage II: radix-4 DIF over n1 (stride 125), 4 stages, natural input order.
    // DIF butterfly: t0=s0+s1, t2=s0-s1, t1=d0-i*d1, t3=d0+i*d1;  u_q = W_L^{jq} t_q.
    // ---- DIF stage 1: L=128, M=32, inter-dim twiddle W_N^{n1*k2} fused on reads ----
    {
        const float ANGN = -6.28318530717958647692f / 16000.0f;
        const float ANGL = -6.28318530717958647692f / 128.0f;
        for (int tau = tid; tau < 125 * 32; tau += nt) {
            int j = tau / 125;
            int k2 = tau - j * 125;
            float2 v[4];
            #pragma unroll
            for (int p = 0; p < 4; ++p) {
                int n1 = j + 32 * p;
                float2 x = ld[n1 * 125 + k2];
                v[p] = cmul(x, cis(ANGN * (float)(n1 * k2)));   // n1*k2 < 16000, exact in fp32
            }
            float2 s0 = cadd(v[0], v[2]), s1 = cadd(v[1], v[3]);
            float2 d0 = csub(v[0], v[2]), d1 = csub(v[1], v[3]);
            float2 t0 = cadd(s0, s1), t2 = csub(s0, s1);
            float2 t1 = make_float2(d0.x + d1.y, d0.y - d1.x);  // d0 - i*d1
            float2 t3 = make_float2(d0.x - d1.y, d0.y + d1.x);  // d0 + i*d1
            float2 w1 = cis(ANGL * (float)j);
            float2 w2 = cmul(w1, w1), w3 = cmul(w2, w1);
            ld[ j       * 125 + k2] = t0;
            ld[(j + 32) * 125 + k2] = cmul(w1, t1);
            ld[(j + 64) * 125 + k2] = cmul(w2, t2);
            ld[(j + 96) * 125 + k2] = cmul(w3, t3);
        }
        __syncthreads();
    }
    // ---- DIF stage 2: L=32, M=8 ----
    {
        const float ANGL = -6.28318530717958647692f / 32.0f;
        for (int tau = tid; tau < 125 * 32; tau += nt) {
            int bf = tau / 125;
            int k2 = tau - bf * 125;
            int j = bf & 7, blk = bf >> 3;
            int base = blk * 32 + j;
            float2 v[4];
            #pragma unroll
            for (int p = 0; p < 4; ++p) v[p] = ld[(base + 8 * p) * 125 + k2];
            float2 s0 = cadd(v[0], v[2]), s1 = cadd(v[1], v[3]);
            float2 d0 = csub(v[0], v[2]), d1 = csub(v[1], v[3]);
            float2 t0 = cadd(s0, s1), t2 = csub(s0, s1);
            float2 t1 = make_float2(d0.x + d1.y, d0.y - d1.x);
            float2 t3 = make_float2(d0.x - d1.y, d0.y + d1.x);
            float2 w1 = cis(ANGL * (float)j);
            float2 w2 = cmul(w1, w1), w3 = cmul(w2, w1);
            ld[(base     ) * 125 + k2] = t0;
            ld[(base +  8) * 125 + k2] = cmul(w1, t1);
            ld[(base + 16) * 125 + k2] = cmul(w2, t2);
            ld[(base + 24) * 125 + k2] = cmul(w3, t3);
        }
        __syncthreads();
    }
    // ---- DIF stage 3: L=8, M=2 ----
    {
        const float ANGL = -6.28318530717958647692f / 8.0f;
        for (int tau = tid; tau < 125 * 32; tau += nt) {
            int bf = tau / 125;
            int k2 = tau - bf * 125;
            int j = bf & 1, blk = bf >> 1;
            int base = blk * 8 + j;
            float2 v[4];
            #pragma unroll
            for (int p = 0; p < 4; ++p) v[p] = ld[(base + 2 * p) * 125 + k2];
            float2 s0 = cadd(v[0], v[2]), s1 = cadd(v[1], v[3]);
            float2 d0 = csub(v[0], v[2]), d1 = csub(v[1], v[3]);
            float2 t0 = cadd(s0, s1), t2 = csub(s0, s1);
            float2 t1 = make_float2(d0.x + d1.y, d0.y - d1.x);
            float2 t3 = make_float2(d0.x - d1.y, d0.y + d1.x);
            float2 w1 = cis(ANGL * (float)j);
            float2 w2 = cmul(w1, w1), w3 = cmul(w2, w1);
            ld[(base    ) * 125 + k2] = t0;
            ld[(base + 2) * 125 + k2] = cmul(w1, t1);
            ld[(base + 4) * 125 + k2] = cmul(w2, t2);
            ld[(base + 6) * 125 + k2] = cmul(w3, t3);
        }
        __syncthreads();
    }
    // ---- DIF stage 4: L=2 (radix-2, no twiddle) ----
    {
        for (int tau = tid; tau < 125 * 64; tau += nt) {
            int blk = tau / 125;
            int k2 = tau - blk * 125;
            int pa = (2 * blk) * 125 + k2, pb = pa + 125;
            float2 a = ld[pa], b = ld[pb];
            ld[pa] = cadd(a, b);
            ld[pb] = csub(a, b);
        }
        __syncthreads();
    }
}

// ---- fused: scatter -> FFT -> pointwise (packed-spectrum unpack) -> IFFT -> real ----
// z[b][p] = y1[b][p] + i*y2[b][p]; F1*F2 = (Z[k]^2 - conj(Z[N-k])^2)/(4i);
// IFFT(G) = conj(FFT(conj(G)))/N. Z is stored digit-scrambled (posn1); the
// pointwise stage reads scrambled and writes FFT-input-permuted — pure index math.
__global__ void __launch_bounds__(1024)
fused_fft(const float* __restrict__ x1, const float* __restrict__ x2,
          const int* __restrict__ idx1, const float* __restrict__ sgn1,
          const int* __restrict__ idx2, const float* __restrict__ sgn2,
          float* __restrict__ out) {
    extern __shared__ float2 ld[];
    const int b = blockIdx.x;
    const int tid = threadIdx.x, nt = blockDim.x;

    for (int i = tid; i < NFFT; i += nt) ld[i] = make_float2(0.f, 0.f);
    __syncthreads();

    const float* x1b = x1 + (size_t)b * DIM;
    const float* x2b = x2 + (size_t)b * DIM;
    for (int d = tid; d < DIM; d += nt) {
        atomicAdd(&ld[perm_slot(idx1[d])].x, sgn1[d] * x1b[d]);
        atomicAdd(&ld[perm_slot(idx2[d])].y, sgn2[d] * x2b[d]);
    }
    __syncthreads();

    fft16000(ld);   // Z at scrambled rows

    float2 vals[8][2];
    int nk = 0;
    for (int k = tid; k <= NFFT / 2; k += nt, ++nk) {
        int k1 = k / 125, k2 = k - 125 * k1;
        int k1m, k2m;
        if (k2 == 0) { k2m = 0;        k1m = (128 - k1) & 127; }
        else         { k2m = 125 - k2; k1m = 127 - k1; }
        float2 Zk = ld[posn1(k1)  * 125 + k2];
        float2 Zm = ld[posn1(k1m) * 125 + k2m];
        float u = (Zk.x * Zk.x - Zk.y * Zk.y) - (Zm.x * Zm.x - Zm.y * Zm.y);
        float v = 2.f * (Zk.x * Zk.y + Zm.x * Zm.y);
        vals[nk][0] = make_float2(0.25f * v,  0.25f * u);   // conj(G)[k]
        vals[nk][1] = make_float2(0.25f * v, -0.25f * u);   // conj(G)[N-k]
    }
    __syncthreads();
    nk = 0;
    for (int k = tid; k <= NFFT / 2; k += nt, ++nk) {
        ld[perm_slot(k)] = vals[nk][0];
        if (k != 0 && k != NFFT / 2)
            ld[perm_slot(NFFT - k)] = vals[nk][1];
    }
    __syncthreads();

    fft16000(ld);   // FFT(conj(G)), scrambled rows; Re(conj(.)) = Re(.)

    const float invN = 1.0f / (float)NFFT;
    float* outb = out + (size_t)b * NFFT;
    for (int k = tid; k < NFFT; k += nt) {
        int k1 = k / 125, k2 = k - 125 * k1;
        outb[k] = ld[posn1(k1) * 125 + k2].x * invN;
    }
}

extern "C" void kernel_launch(void* const* d_in, const int* in_sizes, int n_in,
                              void* d_out, int out_size, void* d_ws, size_t ws_size,
                              hipStream_t stream) {
    (void)in_sizes; (void)n_in; (void)out_size; (void)ws_size;
    const float* x1 = (const float*)d_in[0];
    const float* x2 = (const float*)d_in[1];
    const float* C1 = (const float*)d_in[2];
    const float* C2 = (const float*)d_in[3];
    float* out = (float*)d_out;

    char* w = (char*)d_ws;
    int*    idx1 = (int*)  (w);             // 8 KB
    float*  sgn1 = (float*)(w + 8192);      // 8 KB
    int*    idx2 = (int*)  (w + 16384);     // 8 KB
    float*  sgn2 = (float*)(w + 24576);     // 8 KB

    (void)hipFuncSetAttribute((const void*)fused_fft,
                              hipFuncAttributeMaxDynamicSharedMemorySize, NFFT * 8);

    extract_sketch<<<(2 * DIM) / 4, 256, 0, stream>>>(C1, C2, idx1, sgn1, idx2, sgn2);
    fused_fft     <<<BATCH, 1024, NFFT * 8, stream>>>(x1, x2, idx1, sgn1, idx2, sgn2, out);
}

// Round 4
// 302.032 us; speedup vs baseline: 1.2526x; 1.0595x over previous
//
#include <hip/hip_runtime.h>

#define NFFT 16000   // 128 * 125
#define BATCH 128
#define DIM 2048
#define TP 17        // padded LDS row stride in K3

__device__ __forceinline__ float2 cmul(float2 a, float2 b) {
    return make_float2(a.x * b.x - a.y * b.y, a.x * b.y + a.y * b.x);
}
__device__ __forceinline__ float2 cadd(float2 a, float2 b) { return make_float2(a.x + b.x, a.y + b.y); }
__device__ __forceinline__ float2 csub(float2 a, float2 b) { return make_float2(a.x - b.x, a.y - b.y); }
__device__ __forceinline__ float2 cis(float ang) { return make_float2(__cosf(ang), __sinf(ang)); }

// 3-digit base-5 reversal (involution), n in [0,125)
__device__ __forceinline__ int rev5_3(int n) {
    int d0 = n % 5, r = n / 5;
    int d1 = r % 5, d2 = r / 5;
    return d0 * 25 + d1 * 5 + d2;
}

// packed-spectrum pointwise: conj(G)[k] given Zk=Z[k], Zm=Z[N-k]
// (identical numerics to the R2/R3 passing kernels)
__device__ __forceinline__ float2 conjG(float2 Zk, float2 Zm) {
    float u = (Zk.x * Zk.x - Zk.y * Zk.y) - (Zm.x * Zm.x - Zm.y * Zm.y);
    float v = 2.f * (Zk.x * Zk.y + Zm.x * Zm.y);
    return make_float2(0.25f * v, 0.25f * u);
}

// in-register 128-point DIF FFT across one wave: lane l holds positions l (x0)
// and l+64 (x1); output: x0 = X[rev7(l)], x1 = X[rev7(l)+1]
__device__ __forceinline__ void dif128(float2& x0, float2& x1, int l) {
    const float PI_F = 3.14159265358979323846f;
    {   // stage m=64 (register-local)
        float2 a = x0, b = x1;
        x0 = cadd(a, b);
        float2 d = csub(a, b);
        x1 = cmul(d, cis(-PI_F / 64.0f * (float)l));   // W_128^l
    }
    #pragma unroll
    for (int m = 32; m >= 1; m >>= 1) {
        int j = l & (m - 1);
        bool upper = (l & m) != 0;
        float2 w = cis(-PI_F / (float)m * (float)j);   // W_{2m}^j
        float2 o0, o1;
        o0.x = __shfl_xor(x0.x, m); o0.y = __shfl_xor(x0.y, m);
        o1.x = __shfl_xor(x1.x, m); o1.y = __shfl_xor(x1.y, m);
        if (upper) {
            x0 = cmul(csub(o0, x0), w);
            x1 = cmul(csub(o1, x1), w);
        } else {
            x0 = cadd(x0, o0);
            x1 = cadd(x1, o1);
        }
    }
}

// ---- find the single nonzero (idx, sign) in each row of C1/C2 ----
__global__ void extract_sketch(const float* __restrict__ C1, const float* __restrict__ C2,
                               int* __restrict__ idx1, float* __restrict__ sgn1,
                               int* __restrict__ idx2, float* __restrict__ sgn2) {
    int gwave = (blockIdx.x * blockDim.x + threadIdx.x) >> 6;
    int lane = threadIdx.x & 63;
    if (gwave >= 2 * DIM) return;
    const float* row;
    int* idxp; float* sgnp; int d;
    if (gwave < DIM) { d = gwave;       row = C1 + (size_t)d * NFFT; idxp = idx1; sgnp = sgn1; }
    else             { d = gwave - DIM; row = C2 + (size_t)d * NFFT; idxp = idx2; sgnp = sgn2; }
    for (int step = 0; step < 16; ++step) {
        int off0 = step * 1024 + lane * 4;
        float4 v[4];
        #pragma unroll
        for (int c = 0; c < 4; ++c) {
            int off = off0 + c * 256;
            v[c] = (off < NFFT) ? *reinterpret_cast<const float4*>(row + off)
                                : make_float4(0.f, 0.f, 0.f, 0.f);
        }
        bool found = false;
        #pragma unroll
        for (int c = 0; c < 4; ++c) {
            float4 w = v[c];
            if (w.x != 0.f || w.y != 0.f || w.z != 0.f || w.w != 0.f) {
                int off = off0 + c * 256;
                int j; float s;
                if (w.x != 0.f)      { j = 0; s = w.x; }
                else if (w.y != 0.f) { j = 1; s = w.y; }
                else if (w.z != 0.f) { j = 2; s = w.z; }
                else                 { j = 3; s = w.w; }
                idxp[d] = off + j;
                sgnp[d] = s;
                found = true;
            }
        }
        if (__any(found)) return;
    }
}

// ---- K1: scatter + 125-point column FFTs (over n2) + inter-dim twiddle ----
// grid = 128 b x 4 quarters; block handles n1 in [32q, 32q+32)
// writes U[b][k2*128 + n1] = S[n1][k2] * W_N^{n1*k2}
__global__ void __launch_bounds__(256) k1_colfft(
        const float* __restrict__ x1, const float* __restrict__ x2,
        const int* __restrict__ idx1, const float* __restrict__ sgn1,
        const int* __restrict__ idx2, const float* __restrict__ sgn2,
        float2* __restrict__ U) {
    __shared__ float2 S[32 * 125];
    const int b = blockIdx.x >> 2, q = blockIdx.x & 3;
    const int tid = threadIdx.x;

    for (int i = tid; i < 32 * 125; i += 256) S[i] = make_float2(0.f, 0.f);
    __syncthreads();

    const float* x1b = x1 + (size_t)b * DIM;
    const float* x2b = x2 + (size_t)b * DIM;
    for (int d = tid; d < DIM; d += 256) {
        int p1 = idx1[d]; int n1a = p1 & 127;
        if ((n1a >> 5) == q) atomicAdd(&S[(n1a & 31) * 125 + rev5_3(p1 >> 7)].x, sgn1[d] * x1b[d]);
        int p2 = idx2[d]; int n1b = p2 & 127;
        if ((n1b >> 5) == q) atomicAdd(&S[(n1b & 31) * 125 + rev5_3(p2 >> 7)].y, sgn2[d] * x2b[d]);
    }
    __syncthreads();

    // 3 radix-5 DIT stages per row (digit-reversed input -> natural k2)
    const float C1_5 = 0.30901699437494742f, S1_5 = 0.95105651629515357f;
    const float C2_5 = -0.80901699437494745f, S2_5 = 0.58778525229247312f;
    const float2 w5tab[5] = { make_float2(1.f, 0.f),
                              make_float2(C1_5, -S1_5), make_float2(C2_5, -S2_5),
                              make_float2(C2_5,  S2_5), make_float2(C1_5,  S1_5) };
    #pragma unroll
    for (int s = 0; s < 3; ++s) {
        const int m = (s == 0) ? 1 : (s == 1) ? 5 : 25;
        const float angstep = -6.28318530717958647692f / (float)(5 * m);
        for (int task = tid; task < 32 * 25; task += 256) {
            int row = task / 25;
            int bf = task - row * 25;
            int t = bf % m, blk = bf / m;
            int base = row * 125 + blk * (5 * m) + t;
            float2 xv[5];
            #pragma unroll
            for (int r = 0; r < 5; ++r) xv[r] = S[base + r * m];
            if (m > 1) {
                float2 w1 = cis(angstep * (float)t);
                float2 w2 = cmul(w1, w1), w3 = cmul(w2, w1), w4 = cmul(w2, w2);
                xv[1] = cmul(xv[1], w1); xv[2] = cmul(xv[2], w2);
                xv[3] = cmul(xv[3], w3); xv[4] = cmul(xv[4], w4);
            }
            float2 y[5];
            #pragma unroll
            for (int qq = 0; qq < 5; ++qq) {
                float2 acc = xv[0];
                #pragma unroll
                for (int r = 1; r < 5; ++r) {
                    float2 t2 = cmul(xv[r], w5tab[(qq * r) % 5]);
                    acc.x += t2.x; acc.y += t2.y;
                }
                y[qq] = acc;
            }
            #pragma unroll
            for (int qq = 0; qq < 5; ++qq) S[base + qq * m] = y[qq];
        }
        __syncthreads();
    }

    const float ANGN = -6.28318530717958647692f / 16000.0f;
    const int n1base = q * 32;
    float2* Ub = U + (size_t)b * NFFT;
    for (int i = tid; i < 32 * 125; i += 256) {
        int n1l = i & 31, k2 = i >> 5;
        int n1 = n1base + n1l;
        Ub[k2 * 128 + n1] = cmul(S[n1l * 125 + k2], cis(ANGN * (float)(n1 * k2)));
    }
}

// ---- K2: per-wave column-pair: 128-FFT (fwd) -> pointwise -> 128-FFT (inv start) ----
// wave task = (b, cg): cg=0 -> column 0 (self-paired); cg in [1,62] -> pair (cg, 125-cg)
// writes V[b][m1*128 + j1] = A[m1][j1] * W_N^{m1*j1}
__global__ void __launch_bounds__(256) k2_pair(const float2* __restrict__ U,
                                               float2* __restrict__ V) {
    __shared__ float2 Z[4][2][128];   // [wave][col][row]
    const int w = threadIdx.x >> 6, l = threadIdx.x & 63;
    const int task = blockIdx.x * 4 + w;          // 2016*4 = 8064 = 128*63 exactly
    const int b = task / 63, cg = task - b * 63;
    const int c = cg, cm = (cg == 0) ? 0 : 125 - cg;
    const float2* Ub = U + (size_t)b * NFFT;

    float2 a0 = Ub[c * 128 + l],  a1 = Ub[c * 128 + l + 64];
    float2 b0 = Ub[cm * 128 + l], b1 = Ub[cm * 128 + l + 64];
    dif128(a0, a1, l);
    dif128(b0, b1, l);
    const int e = (int)(__brev((unsigned)l) >> 25);    // rev7(l), even

    Z[w][0][e] = a0; Z[w][0][e + 1] = a1;
    Z[w][1][e] = b0; Z[w][1][e + 1] = b1;
    __syncthreads();

    // pointwise: col c rows e,e+1; col cm rows 126-e,127-e
    float2 gA0, gA1, gB0, gB1;
    if (cg != 0) {
        float2 zm0 = Z[w][1][127 - e];     // partner of (c, e)
        float2 zm1 = Z[w][1][126 - e];     // partner of (c, e+1)
        gA0 = conjG(a0, zm0);
        gA1 = conjG(a1, zm1);
        gB1 = conjG(zm0, a0);              // col cm, row 127-e
        gB0 = conjG(zm1, a1);              // col cm, row 126-e
    } else {
        float2 zm0 = Z[w][0][(128 - e) & 127];
        float2 zm1 = Z[w][0][127 - e];
        gA0 = conjG(a0, zm0);
        gA1 = conjG(a1, zm1);
        gB0 = make_float2(0.f, 0.f); gB1 = make_float2(0.f, 0.f);
    }
    __syncthreads();   // all reads of Z done before overwrite

    Z[w][0][e] = gA0; Z[w][0][e + 1] = gA1;
    if (cg != 0) { Z[w][1][126 - e] = gB0; Z[w][1][127 - e] = gB1; }
    __syncthreads();

    // inverse first stage: 128-FFT over k1 per column (natural input from LDS)
    float2 p0 = Z[w][0][l], p1 = Z[w][0][l + 64];
    float2 q0 = Z[w][1][l], q1 = Z[w][1][l + 64];
    dif128(p0, p1, l);
    dif128(q0, q1, l);

    const float ANGN = -6.28318530717958647692f / 16000.0f;
    float2* Vb = V + (size_t)b * NFFT;
    p0 = cmul(p0, cis(ANGN * (float)(c * e)));
    p1 = cmul(p1, cis(ANGN * (float)(c * (e + 1))));
    *reinterpret_cast<float4*>(&Vb[c * 128 + e]) = make_float4(p0.x, p0.y, p1.x, p1.y);
    if (cg != 0) {
        q0 = cmul(q0, cis(ANGN * (float)(cm * e)));
        q1 = cmul(q1, cis(ANGN * (float)(cm * (e + 1))));
        *reinterpret_cast<float4*>(&Vb[cm * 128 + e]) = make_float4(q0.x, q0.y, q1.x, q1.y);
    }
}

// ---- K3: 125-point row FFTs (over m1) per (b, 16-wide j1 tile); real output ----
// out[b][j1 + 128*j2] = Re(FFT_125(V[b][.][j1]))[j2] / N
__global__ void __launch_bounds__(256) k3_rowfft(const float2* __restrict__ V,
                                                 float* __restrict__ out) {
    __shared__ float2 T[125 * TP];
    const int b = blockIdx.x >> 3, g = blockIdx.x & 7;
    const int j1base = g * 16, tid = threadIdx.x;
    const float2* Vb = V + (size_t)b * NFFT;

    for (int i = tid; i < 125 * 16; i += 256) {
        int m1 = i >> 4, j1l = i & 15;
        T[rev5_3(m1) * TP + j1l] = Vb[m1 * 128 + j1base + j1l];   // digit-reversed load
    }
    __syncthreads();

    const float C1_5 = 0.30901699437494742f, S1_5 = 0.95105651629515357f;
    const float C2_5 = -0.80901699437494745f, S2_5 = 0.58778525229247312f;
    const float2 w5tab[5] = { make_float2(1.f, 0.f),
                              make_float2(C1_5, -S1_5), make_float2(C2_5, -S2_5),
                              make_float2(C2_5,  S2_5), make_float2(C1_5,  S1_5) };
    #pragma unroll
    for (int s = 0; s < 3; ++s) {
        const int m = (s == 0) ? 1 : (s == 1) ? 5 : 25;
        const float angstep = -6.28318530717958647692f / (float)(5 * m);
        for (int task = tid; task < 16 * 25; task += 256) {
            int bf = task >> 4;
            int j1l = task & 15;
            int t = bf % m, blk = bf / m;
            int base = (blk * (5 * m) + t) * TP + j1l;
            float2 xv[5];
            #pragma unroll
            for (int r = 0; r < 5; ++r) xv[r] = T[base + r * m * TP];
            if (m > 1) {
                float2 w1 = cis(angstep * (float)t);
                float2 w2 = cmul(w1, w1), w3 = cmul(w2, w1), w4 = cmul(w2, w2);
                xv[1] = cmul(xv[1], w1); xv[2] = cmul(xv[2], w2);
                xv[3] = cmul(xv[3], w3); xv[4] = cmul(xv[4], w4);
            }
            float2 y[5];
            #pragma unroll
            for (int qq = 0; qq < 5; ++qq) {
                float2 acc = xv[0];
                #pragma unroll
                for (int r = 1; r < 5; ++r) {
                    float2 t2 = cmul(xv[r], w5tab[(qq * r) % 5]);
                    acc.x += t2.x; acc.y += t2.y;
                }
                y[qq] = acc;
            }
            #pragma unroll
            for (int qq = 0; qq < 5; ++qq) T[base + qq * m * TP] = y[qq];
        }
        __syncthreads();
    }

    const float invN = 1.0f / (float)NFFT;
    float* outb = out + (size_t)b * NFFT;
    for (int i = tid; i < 125 * 16; i += 256) {
        int j2 = i >> 4, j1l = i & 15;
        outb[j1base + j1l + 128 * j2] = T[j2 * TP + j1l].x * invN;
    }
}

extern "C" void kernel_launch(void* const* d_in, const int* in_sizes, int n_in,
                              void* d_out, int out_size, void* d_ws, size_t ws_size,
                              hipStream_t stream) {
    (void)in_sizes; (void)n_in; (void)out_size; (void)ws_size;
    const float* x1 = (const float*)d_in[0];
    const float* x2 = (const float*)d_in[1];
    const float* C1 = (const float*)d_in[2];
    const float* C2 = (const float*)d_in[3];
    float* out = (float*)d_out;

    char* w = (char*)d_ws;
    int*    idx1 = (int*)  (w);                       // 8 KB
    float*  sgn1 = (float*)(w + 8192);                // 8 KB
    int*    idx2 = (int*)  (w + 16384);               // 8 KB
    float*  sgn2 = (float*)(w + 24576);               // 8 KB
    float2* U    = (float2*)(w + 32768);              // 16.384 MB
    float2* V    = (float2*)(w + 32768 + 16384000);   // 16.384 MB

    extract_sketch<<<(2 * DIM) / 4, 256, 0, stream>>>(C1, C2, idx1, sgn1, idx2, sgn2);
    k1_colfft     <<<BATCH * 4, 256, 0, stream>>>(x1, x2, idx1, sgn1, idx2, sgn2, U);
    k2_pair       <<<2016, 256, 0, stream>>>(U, V);
    k3_rowfft     <<<BATCH * 8, 256, 0, stream>>>(V, out);
}

// Round 5
// 293.416 us; speedup vs baseline: 1.2894x; 1.0294x over previous
//
#include <hip/hip_runtime.h>

#define NFFT 16000   // 128 * 125
#define BATCH 128
#define DIM 2048
#define TP 17        // padded LDS row stride in K3

__device__ __forceinline__ float2 cmul(float2 a, float2 b) {
    return make_float2(a.x * b.x - a.y * b.y, a.x * b.y + a.y * b.x);
}
__device__ __forceinline__ float2 cadd(float2 a, float2 b) { return make_float2(a.x + b.x, a.y + b.y); }
__device__ __forceinline__ float2 csub(float2 a, float2 b) { return make_float2(a.x - b.x, a.y - b.y); }
__device__ __forceinline__ float2 cis(float ang) { return make_float2(__cosf(ang), __sinf(ang)); }

__device__ __forceinline__ int rev5_3(int n) {
    int d0 = n % 5, r = n / 5;
    int d1 = r % 5, d2 = r / 5;
    return d0 * 25 + d1 * 5 + d2;
}
__device__ __forceinline__ int rev7(int x) { return (int)(__brev((unsigned)x) >> 25); }

__device__ __forceinline__ float2 shfl2(float2 v, int lane) {
    return make_float2(__shfl(v.x, lane), __shfl(v.y, lane));
}
__device__ __forceinline__ float2 shfl2_xor(float2 v, int mask) {
    return make_float2(__shfl_xor(v.x, mask), __shfl_xor(v.y, mask));
}

// packed-spectrum pointwise: conj(G)[k] given Zk=Z[k], Zm=Z[N-k]
__device__ __forceinline__ float2 conjG(float2 Zk, float2 Zm) {
    float u = (Zk.x * Zk.x - Zk.y * Zk.y) - (Zm.x * Zm.x - Zm.y * Zm.y);
    float v = 2.f * (Zk.x * Zk.y + Zm.x * Zm.y);
    return make_float2(0.25f * v, 0.25f * u);
}

// in-register 128-point DIF FFT across one wave; twiddles hoisted (lane-only).
// lane l holds positions l (x0), l+64 (x1); output: x0=X[rev7(l)], x1=X[rev7(l)+1]
__device__ __forceinline__ void dif128(float2& x0, float2& x1, const float2* tw, int l) {
    {   // stage m=64 (register-local)
        float2 a = x0, b = x1;
        x0 = cadd(a, b);
        x1 = cmul(csub(a, b), tw[0]);
    }
    int s = 1;
    #pragma unroll
    for (int m = 32; m >= 1; m >>= 1, ++s) {
        float2 w = tw[s];
        float2 o0 = shfl2_xor(x0, m), o1 = shfl2_xor(x1, m);
        if (l & m) {
            x0 = cmul(csub(o0, x0), w);
            x1 = cmul(csub(o1, x1), w);
        } else {
            x0 = cadd(x0, o0);
            x1 = cadd(x1, o1);
        }
    }
}

// ---- find the single nonzero (idx, sign) in each row of C1/C2 ----
__global__ void extract_sketch(const float* __restrict__ C1, const float* __restrict__ C2,
                               int* __restrict__ idx1, float* __restrict__ sgn1,
                               int* __restrict__ idx2, float* __restrict__ sgn2) {
    int gwave = (blockIdx.x * blockDim.x + threadIdx.x) >> 6;
    int lane = threadIdx.x & 63;
    if (gwave >= 2 * DIM) return;
    const float* row;
    int* idxp; float* sgnp; int d;
    if (gwave < DIM) { d = gwave;       row = C1 + (size_t)d * NFFT; idxp = idx1; sgnp = sgn1; }
    else             { d = gwave - DIM; row = C2 + (size_t)d * NFFT; idxp = idx2; sgnp = sgn2; }
    for (int step = 0; step < 16; ++step) {
        int off0 = step * 1024 + lane * 4;
        float4 v[4];
        #pragma unroll
        for (int c = 0; c < 4; ++c) {
            int off = off0 + c * 256;
            v[c] = (off < NFFT) ? *reinterpret_cast<const float4*>(row + off)
                                : make_float4(0.f, 0.f, 0.f, 0.f);
        }
        bool found = false;
        #pragma unroll
        for (int c = 0; c < 4; ++c) {
            float4 w = v[c];
            if (w.x != 0.f || w.y != 0.f || w.z != 0.f || w.w != 0.f) {
                int off = off0 + c * 256;
                int j; float s;
                if (w.x != 0.f)      { j = 0; s = w.x; }
                else if (w.y != 0.f) { j = 1; s = w.y; }
                else if (w.z != 0.f) { j = 2; s = w.z; }
                else                 { j = 3; s = w.w; }
                idxp[d] = off + j;
                sgnp[d] = s;
                found = true;
            }
        }
        if (__any(found)) return;
    }
}

// ---- K1: scatter + 125-point column FFTs (over n2) + inter-dim twiddle ----
// grid = 128 b x 4 quarters, 512 threads; writes U[b][k2*128 + n1] = S[n1][k2]*W_N^{n1*k2}
__global__ void __launch_bounds__(512) k1_colfft(
        const float* __restrict__ x1, const float* __restrict__ x2,
        const int* __restrict__ idx1, const float* __restrict__ sgn1,
        const int* __restrict__ idx2, const float* __restrict__ sgn2,
        float2* __restrict__ U) {
    __shared__ float2 S[32 * 125];
    const int b = blockIdx.x >> 2, q = blockIdx.x & 3;
    const int tid = threadIdx.x;

    for (int i = tid; i < 32 * 125; i += 512) S[i] = make_float2(0.f, 0.f);
    __syncthreads();

    const float* x1b = x1 + (size_t)b * DIM;
    const float* x2b = x2 + (size_t)b * DIM;
    for (int d = tid; d < DIM; d += 512) {
        int p1 = idx1[d]; int n1a = p1 & 127;
        if ((n1a >> 5) == q) atomicAdd(&S[(n1a & 31) * 125 + rev5_3(p1 >> 7)].x, sgn1[d] * x1b[d]);
        int p2 = idx2[d]; int n1b = p2 & 127;
        if ((n1b >> 5) == q) atomicAdd(&S[(n1b & 31) * 125 + rev5_3(p2 >> 7)].y, sgn2[d] * x2b[d]);
    }
    __syncthreads();

    const float C1_5 = 0.30901699437494742f, S1_5 = 0.95105651629515357f;
    const float C2_5 = -0.80901699437494745f, S2_5 = 0.58778525229247312f;
    const float2 w5tab[5] = { make_float2(1.f, 0.f),
                              make_float2(C1_5, -S1_5), make_float2(C2_5, -S2_5),
                              make_float2(C2_5,  S2_5), make_float2(C1_5,  S1_5) };
    #pragma unroll
    for (int s = 0; s < 3; ++s) {
        const int m = (s == 0) ? 1 : (s == 1) ? 5 : 25;
        const float angstep = -6.28318530717958647692f / (float)(5 * m);
        for (int task = tid; task < 32 * 25; task += 512) {
            int row = task / 25;
            int bf = task - row * 25;
            int t = bf % m, blk = bf / m;
            int base = row * 125 + blk * (5 * m) + t;
            float2 xv[5];
            #pragma unroll
            for (int r = 0; r < 5; ++r) xv[r] = S[base + r * m];
            if (m > 1) {
                float2 w1 = cis(angstep * (float)t);
                float2 w2 = cmul(w1, w1), w3 = cmul(w2, w1), w4 = cmul(w2, w2);
                xv[1] = cmul(xv[1], w1); xv[2] = cmul(xv[2], w2);
                xv[3] = cmul(xv[3], w3); xv[4] = cmul(xv[4], w4);
            }
            float2 y[5];
            #pragma unroll
            for (int qq = 0; qq < 5; ++qq) {
                float2 acc = xv[0];
                #pragma unroll
                for (int r = 1; r < 5; ++r) {
                    float2 t2 = cmul(xv[r], w5tab[(qq * r) % 5]);
                    acc.x += t2.x; acc.y += t2.y;
                }
                y[qq] = acc;
            }
            #pragma unroll
            for (int qq = 0; qq < 5; ++qq) S[base + qq * m] = y[qq];
        }
        __syncthreads();
    }

    const float ANGN = -6.28318530717958647692f / 16000.0f;
    const int n1base = q * 32;
    float2* Ub = U + (size_t)b * NFFT;
    for (int i = tid; i < 32 * 125; i += 512) {
        int n1l = i & 31, k2 = i >> 5;
        int n1 = n1base + n1l;
        Ub[k2 * 128 + n1] = cmul(S[n1l * 125 + k2], cis(ANGN * (float)(n1 * k2)));
    }
}

// ---- K2: per-wave column-pair, zero-LDS zero-barrier ----
// fwd 128-FFT -> pointwise (partner rows via shfl) -> inverse-start 128-FFT
// writes V[b][m1*128 + j1] = A[m1][j1] * W_N^{m1*j1}
__global__ void __launch_bounds__(256) k2_pair(const float2* __restrict__ U,
                                               float2* __restrict__ V) {
    const int w = threadIdx.x >> 6, l = threadIdx.x & 63;
    const int task = blockIdx.x * 4 + w;          // 2016*4 = 8064 = 128*63 exactly
    const int b = task / 63, cg = task - b * 63;
    const int c = cg, cm = cg ? 125 - cg : 0;
    const float2* Ub = U + (size_t)b * NFFT;
    const float PI_F = 3.14159265358979323846f;

    // hoisted dif128 twiddles (lane-only), reused across all 4 FFT calls
    float2 tw[7];
    tw[0] = cis(-PI_F / 64.0f * (float)l);
    {
        int m = 32;
        #pragma unroll
        for (int s = 1; s < 7; ++s, m >>= 1)
            tw[s] = cis(-PI_F / (float)m * (float)(l & (m - 1)));
    }

    float2 a0 = Ub[c * 128 + l], a1 = Ub[c * 128 + l + 64];
    dif128(a0, a1, tw, l);
    float2 b0, b1;
    if (cg) {
        b0 = Ub[cm * 128 + l]; b1 = Ub[cm * 128 + l + 64];
        dif128(b0, b1, tw, l);
    }

    const int e  = rev7(l);           // even; lane holds rows e, e+1
    const int lp = rev7(126 - e);     // holder lane of rows 126-e (reg0) / 127-e (reg1)

    // pointwise: partner of (col,row)=(c,r) is (125-c, 127-r) for c!=0
    float2 gA0, gA1, gB0, gB1;
    if (cg) {
        float2 zm0 = shfl2(b1, lp);   // Zcm[127-e]
        float2 zm1 = shfl2(b0, lp);   // Zcm[126-e]
        gA0 = conjG(a0, zm0);         // G'_c[e]
        gA1 = conjG(a1, zm1);         // G'_c[e+1]
        float2 ym0 = shfl2(a1, lp);   // Zc[127-e]
        float2 ym1 = shfl2(a0, lp);   // Zc[126-e]
        gB0 = conjG(b0, ym0);         // G'_cm[e]
        gB1 = conjG(b1, ym1);         // G'_cm[e+1]
    } else {
        int hz = rev7((128 - e) & 127);
        float2 zm0 = shfl2(a0, hz);   // Z0[(128-e)&127]
        float2 zm1 = shfl2(a1, lp);   // Z0[127-e]
        gA0 = conjG(a0, zm0);
        gA1 = conjG(a1, zm1);
        gB0 = gB1 = make_float2(0.f, 0.f);
    }

    // re-permute bit-reversed G' back to natural order for the inverse-start FFT:
    // G'[l] / G'[l+64] live as reg (l&1 ? 1 : 0) of lane q / q+1, q = rev7(l&~1)
    const int q = rev7(l & 62);
    const float ANGN = -6.28318530717958647692f / 16000.0f;
    float2* Vb = V + (size_t)b * NFFT;

    {
        float2 t00 = shfl2(gA0, q),     t10 = shfl2(gA1, q);
        float2 t01 = shfl2(gA0, q + 1), t11 = shfl2(gA1, q + 1);
        float2 p0 = (l & 1) ? t10 : t00;
        float2 p1 = (l & 1) ? t11 : t01;
        dif128(p0, p1, tw, l);
        p0 = cmul(p0, cis(ANGN * (float)(c * e)));
        p1 = cmul(p1, cis(ANGN * (float)(c * (e + 1))));
        *reinterpret_cast<float4*>(&Vb[c * 128 + e]) = make_float4(p0.x, p0.y, p1.x, p1.y);
    }
    if (cg) {
        float2 t00 = shfl2(gB0, q),     t10 = shfl2(gB1, q);
        float2 t01 = shfl2(gB0, q + 1), t11 = shfl2(gB1, q + 1);
        float2 p0 = (l & 1) ? t10 : t00;
        float2 p1 = (l & 1) ? t11 : t01;
        dif128(p0, p1, tw, l);
        p0 = cmul(p0, cis(ANGN * (float)(cm * e)));
        p1 = cmul(p1, cis(ANGN * (float)(cm * (e + 1))));
        *reinterpret_cast<float4*>(&Vb[cm * 128 + e]) = make_float4(p0.x, p0.y, p1.x, p1.y);
    }
}

// ---- K3: 125-point row FFTs (over m1) per (b, 16-wide j1 tile); real output ----
__global__ void __launch_bounds__(256) k3_rowfft(const float2* __restrict__ V,
                                                 float* __restrict__ out) {
    __shared__ float2 T[125 * TP];
    const int b = blockIdx.x >> 3, g = blockIdx.x & 7;
    const int j1base = g * 16, tid = threadIdx.x;
    const float2* Vb = V + (size_t)b * NFFT;

    for (int i = tid; i < 125 * 16; i += 256) {
        int m1 = i >> 4, j1l = i & 15;
        T[rev5_3(m1) * TP + j1l] = Vb[m1 * 128 + j1base + j1l];
    }
    __syncthreads();

    const float C1_5 = 0.30901699437494742f, S1_5 = 0.95105651629515357f;
    const float C2_5 = -0.80901699437494745f, S2_5 = 0.58778525229247312f;
    const float2 w5tab[5] = { make_float2(1.f, 0.f),
                              make_float2(C1_5, -S1_5), make_float2(C2_5, -S2_5),
                              make_float2(C2_5,  S2_5), make_float2(C1_5,  S1_5) };
    #pragma unroll
    for (int s = 0; s < 3; ++s) {
        const int m = (s == 0) ? 1 : (s == 1) ? 5 : 25;
        const float angstep = -6.28318530717958647692f / (float)(5 * m);
        for (int task = tid; task < 16 * 25; task += 256) {
            int bf = task >> 4;
            int j1l = task & 15;
            int t = bf % m, blk = bf / m;
            int base = (blk * (5 * m) + t) * TP + j1l;
            float2 xv[5];
            #pragma unroll
            for (int r = 0; r < 5; ++r) xv[r] = T[base + r * m * TP];
            if (m > 1) {
                float2 w1 = cis(angstep * (float)t);
                float2 w2 = cmul(w1, w1), w3 = cmul(w2, w1), w4 = cmul(w2, w2);
                xv[1] = cmul(xv[1], w1); xv[2] = cmul(xv[2], w2);
                xv[3] = cmul(xv[3], w3); xv[4] = cmul(xv[4], w4);
            }
            float2 y[5];
            #pragma unroll
            for (int qq = 0; qq < 5; ++qq) {
                float2 acc = xv[0];
                #pragma unroll
                for (int r = 1; r < 5; ++r) {
                    float2 t2 = cmul(xv[r], w5tab[(qq * r) % 5]);
                    acc.x += t2.x; acc.y += t2.y;
                }
                y[qq] = acc;
            }
            #pragma unroll
            for (int qq = 0; qq < 5; ++qq) T[base + qq * m * TP] = y[qq];
        }
        __syncthreads();
    }

    const float invN = 1.0f / (float)NFFT;
    float* outb = out + (size_t)b * NFFT;
    for (int i = tid; i < 125 * 16; i += 256) {
        int j2 = i >> 4, j1l = i & 15;
        outb[j1base + j1l + 128 * j2] = T[j2 * TP + j1l].x * invN;
    }
}

extern "C" void kernel_launch(void* const* d_in, const int* in_sizes, int n_in,
                              void* d_out, int out_size, void* d_ws, size_t ws_size,
                              hipStream_t stream) {
    (void)in_sizes; (void)n_in; (void)out_size; (void)ws_size;
    const float* x1 = (const float*)d_in[0];
    const float* x2 = (const float*)d_in[1];
    const float* C1 = (const float*)d_in[2];
    const float* C2 = (const float*)d_in[3];
    float* out = (float*)d_out;

    char* w = (char*)d_ws;
    int*    idx1 = (int*)  (w);                       // 8 KB
    float*  sgn1 = (float*)(w + 8192);                // 8 KB
    int*    idx2 = (int*)  (w + 16384);               // 8 KB
    float*  sgn2 = (float*)(w + 24576);               // 8 KB
    float2* U    = (float2*)(w + 32768);              // 16.384 MB
    float2* V    = (float2*)(w + 32768 + 16384000);   // 16.384 MB

    extract_sketch<<<(2 * DIM) / 4, 256, 0, stream>>>(C1, C2, idx1, sgn1, idx2, sgn2);
    k1_colfft     <<<BATCH * 4, 512, 0, stream>>>(x1, x2, idx1, sgn1, idx2, sgn2, U);
    k2_pair       <<<2016, 256, 0, stream>>>(U, V);
    k3_rowfft     <<<BATCH * 8, 256, 0, stream>>>(V, out);
}